// Round 1
// baseline (2727.354 us; speedup 1.0000x reference)
//
#include <hip/hip_runtime.h>
#include <hip/hip_bf16.h>

// LogVAE: init Linear+LeakyReLU+LN -> encoder LSTM (S=1024) -> mu/logvar/latent
// -> decoder LSTM (S-1=1023) -> act/time heads.
// Recurrence: 16 WGs x 16 batch, weights persistent in MFMA B-frags (K=192:
// Whh||Wih folded), h double-buffered in LDS bf16, 1 barrier/step.

#define B_ 256
#define S_ 1024
#define NF_ 32
#define E_ 64
#define H_ 128
#define L_ 64
#define C_ 31

#define ACTS_OFF 0
#define TS_OFF   8118528   // 256*1023*31
#define MU_OFF   8380416   // + 256*1023
#define LV_OFF   8396800   // + 256*64

typedef __attribute__((ext_vector_type(8))) short short8;
typedef __attribute__((ext_vector_type(4))) float float4v;

__device__ inline unsigned short f2bf(float x){
  union { float f; unsigned u; } a; a.f = x;
  unsigned r = a.u + 0x7FFFu + ((a.u >> 16) & 1u);
  return (unsigned short)(r >> 16);
}
__device__ inline float frcp(float x){
#if __has_builtin(__builtin_amdgcn_rcpf)
  return __builtin_amdgcn_rcpf(x);
#else
  return 1.0f / x;
#endif
}
__device__ inline float fsig(float x){ return frcp(1.0f + __expf(-x)); }
__device__ inline float ftanh(float x){ return 1.0f - 2.0f*frcp(1.0f + __expf(2.0f*x)); }
__device__ inline float leaky(float x){ return x >= 0.0f ? x : 0.01f*x; }
__device__ inline float wredsum(float v){
  v += __shfl_xor(v, 32, 64);
  v += __shfl_xor(v, 16, 64);
  v += __shfl_xor(v,  8, 64);
  v += __shfl_xor(v,  4, 64);
  v += __shfl_xor(v,  2, 64);
  v += __shfl_xor(v,  1, 64);
  return v;
}

// ---------------- Kernel A: x_emb = LN(leaky(x @ W.T + b)) -> bf16 [S][B][E] --
__global__ __launch_bounds__(256) void init_kernel(
    const float* __restrict__ x, const float* __restrict__ W,
    const float* __restrict__ bias, const float* __restrict__ gam,
    const float* __restrict__ beta, unsigned short* __restrict__ xemb)
{
  const int wave = threadIdx.x >> 6, lane = threadIdx.x & 63;
  const int r = blockIdx.x * 4 + wave;        // r = b*S + s (matches x layout)
  const int b = r >> 10, s = r & 1023;
  const float* xr = x + (size_t)r * NF_;
  float xv = (lane < NF_) ? xr[lane] : 0.0f;
  float acc = bias[lane];
  const float* wr = W + lane * NF_;
  #pragma unroll
  for (int k = 0; k < NF_; ++k)
    acc += __shfl(xv, k, 64) * wr[k];
  acc = leaky(acc);
  float m = wredsum(acc) * (1.0f/64.0f);
  float d = acc - m;
  float v = wredsum(d*d) * (1.0f/64.0f);
  float y = d * rsqrtf(v + 1e-5f) * gam[lane] + beta[lane];
  xemb[((size_t)s * B_ + b) * E_ + lane] = f2bf(y);   // transposed [S][B][E]
}

// ---------------- Kernel B: LSTM recurrence ---------------------------------
// grid=16, block=512 (8 waves). Wave w owns i,f,g,o gates of hidden [16w,16w+16).
__global__ __launch_bounds__(512, 2) void lstm_kernel(
    const float* __restrict__ Wih,   // [512][64]
    const float* __restrict__ Whh,   // [512][128]
    const float* __restrict__ bih, const float* __restrict__ bhh,
    const unsigned short* __restrict__ xemb,  // [>=T][256][64] bf16
    int T,
    const float* __restrict__ h0, const float* __restrict__ c0, // null => ones/zeros
    float* __restrict__ hT_out,               // [256][128] fp32 or null
    unsigned short* __restrict__ hs_out)      // [T][256][128] bf16 or null
{
  __shared__ unsigned short hbuf[2][16*136];  // double buffer, +8 pad -> conflict-free b128
  const int tid = threadIdx.x;
  const int wave = tid >> 6, lane = tid & 63;
  const int quad = lane >> 4, c16 = lane & 15;
  const int bt0 = blockIdx.x * 16;
  const int hu = wave * 16 + c16;

  // Persistent B fragments: B[k][n=gatecol], n=lane&15, k=quad*8+j, kb 0..3=Whh, 4..5=Wih
  short8 Bf[4][6];
  float bias[4];
  #pragma unroll
  for (int g = 0; g < 4; ++g){
    const int gcol = g*128 + hu;
    bias[g] = bih[gcol] + bhh[gcol];
    #pragma unroll
    for (int kb = 0; kb < 6; ++kb){
      union { short8 v; unsigned short u[8]; } tmp;
      #pragma unroll
      for (int j = 0; j < 8; ++j){
        int k = kb*32 + quad*8 + j;
        float w = (kb < 4) ? Whh[gcol*H_ + k] : Wih[gcol*E_ + (k - H_)];
        tmp.u[j] = f2bf(w);
      }
      Bf[g][kb] = tmp.v;
    }
  }

  // init h (LDS) and c (regs, C-frag layout: row=quad*4+r, col=hu)
  if (h0){
    for (int idx = tid; idx < 16*H_; idx += 512){
      int b = idx >> 7, k = idx & 127;
      hbuf[0][b*136 + k] = f2bf(h0[(size_t)(bt0 + b)*H_ + k]);
    }
  } else {
    for (int idx = tid; idx < 16*H_; idx += 512){
      int b = idx >> 7, k = idx & 127;
      hbuf[0][b*136 + k] = 0x3F80;  // bf16(1.0)
    }
  }
  float cst[4];
  #pragma unroll
  for (int r = 0; r < 4; ++r)
    cst[r] = c0 ? c0[(size_t)(bt0 + quad*4 + r)*H_ + hu] : 0.0f;
  __syncthreads();

  // x fragment for t=0 (A layout: m=lane&15=batch, k=quad*8+j)
  short8 xf0, xf1;
  {
    const unsigned short* xp = xemb + ((size_t)(bt0 + c16))*E_ + quad*8;
    xf0 = *(const short8*)xp;
    xf1 = *(const short8*)(xp + 32);
  }

  for (int t = 0; t < T; ++t){
    const int cur = t & 1;
    const unsigned short* hb = hbuf[cur];
    short8 Af[4];
    #pragma unroll
    for (int kb = 0; kb < 4; ++kb)
      Af[kb] = *(const short8*)(hb + c16*136 + kb*32 + quad*8);

    short8 nx0 = xf0, nx1 = xf1;
    if (t + 1 < T){
      const unsigned short* xp = xemb + ((size_t)(t+1)*B_ + bt0 + c16)*E_ + quad*8;
      nx0 = *(const short8*)xp;
      nx1 = *(const short8*)(xp + 32);
    }

    float4v acc[4];
    #pragma unroll
    for (int g = 0; g < 4; ++g) acc[g] = (float4v){bias[g], bias[g], bias[g], bias[g]};
    #pragma unroll
    for (int kb = 0; kb < 4; ++kb){
      #pragma unroll
      for (int g = 0; g < 4; ++g)
        acc[g] = __builtin_amdgcn_mfma_f32_16x16x32_bf16(Af[kb], Bf[g][kb], acc[g], 0, 0, 0);
    }
    #pragma unroll
    for (int g = 0; g < 4; ++g){
      acc[g] = __builtin_amdgcn_mfma_f32_16x16x32_bf16(xf0, Bf[g][4], acc[g], 0, 0, 0);
      acc[g] = __builtin_amdgcn_mfma_f32_16x16x32_bf16(xf1, Bf[g][5], acc[g], 0, 0, 0);
    }

    unsigned short* hw = hbuf[1 - cur];
    #pragma unroll
    for (int r = 0; r < 4; ++r){
      float ig = fsig(acc[0][r]);
      float fg = fsig(acc[1][r]);
      float gg = ftanh(acc[2][r]);
      float og = fsig(acc[3][r]);
      float cn = fg*cst[r] + ig*gg;
      cst[r] = cn;
      float hn = og * ftanh(cn);
      int b = quad*4 + r;
      unsigned short hbits = f2bf(hn);
      hw[b*136 + hu] = hbits;
      if (hs_out) hs_out[((size_t)t*B_ + bt0 + b)*H_ + hu] = hbits;
      if (hT_out && t == T-1) hT_out[(size_t)(bt0 + b)*H_ + hu] = hn;  // fp32, no bf16 loss
    }
    xf0 = nx0; xf1 = nx1;
    __syncthreads();
  }
}

// ---------------- Kernel C: mu/logvar/latent/dh0/dc0 ------------------------
__global__ __launch_bounds__(128) void latent_kernel(
    const float* __restrict__ hT, const float* __restrict__ eps,
    const float* __restrict__ mu_W, const float* __restrict__ mu_b,
    const float* __restrict__ mu_g, const float* __restrict__ mu_be,
    const float* __restrict__ lv_W, const float* __restrict__ lv_b,
    const float* __restrict__ lv_g, const float* __restrict__ lv_be,
    const float* __restrict__ lh_W, const float* __restrict__ lh_b,
    const float* __restrict__ lh_g, const float* __restrict__ lh_be,
    const float* __restrict__ lc_W, const float* __restrict__ lc_b,
    const float* __restrict__ lc_g, const float* __restrict__ lc_be,
    float* __restrict__ out, float* __restrict__ dh0, float* __restrict__ dc0)
{
  const int b = blockIdx.x, tid = threadIdx.x;
  const int wave = tid >> 6, lane = tid & 63;
  __shared__ float shT[H_];
  __shared__ float smu[L_], slv[L_], slat[L_];
  __shared__ float part[2];
  shT[tid] = hT[(size_t)b*H_ + tid];
  __syncthreads();
  {
    const float* W = wave ? lv_W : mu_W;
    float a = (wave ? lv_b : mu_b)[lane];
    for (int k = 0; k < H_; ++k) a += shT[k] * W[lane*H_ + k];
    a = leaky(a);
    float m = wredsum(a) * (1.0f/L_);
    float d = a - m;
    float v = wredsum(d*d) * (1.0f/L_);
    float y = d * rsqrtf(v + 1e-5f) * (wave ? lv_g : mu_g)[lane] + (wave ? lv_be : mu_be)[lane];
    out[(wave ? LV_OFF : MU_OFF) + (size_t)b*L_ + lane] = y;
    if (wave) slv[lane] = y; else smu[lane] = y;
  }
  __syncthreads();
  if (tid < L_) slat[tid] = smu[tid] + eps[(size_t)b*L_ + tid] * __expf(0.5f*slv[tid]);
  __syncthreads();
  #pragma unroll 1
  for (int which = 0; which < 2; ++which){
    const float* W = which ? lc_W : lh_W;
    float p = (which ? lc_b : lh_b)[tid];
    for (int k = 0; k < L_; ++k) p += slat[k] * W[tid*L_ + k];
    p = leaky(p);
    float s = wredsum(p);
    if (lane == 0) part[wave] = s;
    __syncthreads();
    float mean = (part[0] + part[1]) * (1.0f/H_);
    __syncthreads();
    float d = p - mean;
    float s2 = wredsum(d*d);
    if (lane == 0) part[wave] = s2;
    __syncthreads();
    float var = (part[0] + part[1]) * (1.0f/H_);
    __syncthreads();
    float y = d * rsqrtf(var + 1e-5f) * (which ? lc_g : lh_g)[tid] + (which ? lc_be : lh_be)[tid];
    (which ? dc0 : dh0)[(size_t)b*H_ + tid] = y;
  }
}

// ---------------- Kernel D: acts/ts heads via MFMA (N=32: 31 acts + ts) -----
__global__ __launch_bounds__(256) void out_kernel(
    const unsigned short* __restrict__ hs,   // [1023][256][128] bf16
    const float* __restrict__ actW, const float* __restrict__ actB,
    const float* __restrict__ timeW, const float* __restrict__ timeB,
    float* __restrict__ out)
{
  const int wave = threadIdx.x >> 6, lane = threadIdx.x & 63;
  const int quad = lane >> 4, c16 = lane & 15;
  const int mt = blockIdx.x * 4 + wave;      // M-tile of 16 rows (r = t*256 + b)
  short8 Wf[2][4]; float biasn[2];
  #pragma unroll
  for (int ti = 0; ti < 2; ++ti){
    const int n = ti*16 + c16;
    biasn[ti] = (n < C_) ? actB[n] : timeB[0];
    #pragma unroll
    for (int kb = 0; kb < 4; ++kb){
      union { short8 v; unsigned short u[8]; } tmp;
      #pragma unroll
      for (int j = 0; j < 8; ++j){
        int k = kb*32 + quad*8 + j;
        tmp.u[j] = f2bf((n < C_) ? actW[n*H_ + k] : timeW[k]);
      }
      Wf[ti][kb] = tmp.v;
    }
  }
  const unsigned short* hp = hs + ((size_t)mt*16 + c16)*H_ + quad*8;
  float4v acc[2];
  #pragma unroll
  for (int ti = 0; ti < 2; ++ti) acc[ti] = (float4v){biasn[ti], biasn[ti], biasn[ti], biasn[ti]};
  #pragma unroll
  for (int kb = 0; kb < 4; ++kb){
    short8 a = *(const short8*)(hp + kb*32);
    acc[0] = __builtin_amdgcn_mfma_f32_16x16x32_bf16(a, Wf[0][kb], acc[0], 0, 0, 0);
    acc[1] = __builtin_amdgcn_mfma_f32_16x16x32_bf16(a, Wf[1][kb], acc[1], 0, 0, 0);
  }
  #pragma unroll
  for (int ti = 0; ti < 2; ++ti){
    const int n = ti*16 + c16;
    #pragma unroll
    for (int r = 0; r < 4; ++r){
      int rr = mt*16 + quad*4 + r;
      int tt = rr >> 8, b = rr & 255;
      float v = acc[ti][r];
      if (n < C_) out[ACTS_OFF + ((size_t)b*1023 + tt)*C_ + n] = v;
      else        out[TS_OFF + (size_t)b*1023 + tt] = v;
    }
  }
}

// ---------------- launch ----------------------------------------------------
extern "C" void kernel_launch(void* const* d_in, const int* in_sizes, int n_in,
                              void* d_out, int out_size, void* d_ws, size_t ws_size,
                              hipStream_t stream)
{
  (void)in_sizes; (void)n_in; (void)out_size; (void)ws_size;
  const float* x       = (const float*)d_in[0];
  const float* eps     = (const float*)d_in[1];
  const float* init_W  = (const float*)d_in[2];
  const float* init_b  = (const float*)d_in[3];
  const float* init_g  = (const float*)d_in[4];
  const float* init_be = (const float*)d_in[5];
  const float* enc_Wih = (const float*)d_in[6];
  const float* enc_Whh = (const float*)d_in[7];
  const float* enc_bih = (const float*)d_in[8];
  const float* enc_bhh = (const float*)d_in[9];
  const float* mu_W  = (const float*)d_in[10];
  const float* mu_b  = (const float*)d_in[11];
  const float* mu_g  = (const float*)d_in[12];
  const float* mu_be = (const float*)d_in[13];
  const float* lv_W  = (const float*)d_in[14];
  const float* lv_b  = (const float*)d_in[15];
  const float* lv_g  = (const float*)d_in[16];
  const float* lv_be = (const float*)d_in[17];
  const float* dec_Wih = (const float*)d_in[18];
  const float* dec_Whh = (const float*)d_in[19];
  const float* dec_bih = (const float*)d_in[20];
  const float* dec_bhh = (const float*)d_in[21];
  const float* lh_W  = (const float*)d_in[22];
  const float* lh_b  = (const float*)d_in[23];
  const float* lh_g  = (const float*)d_in[24];
  const float* lh_be = (const float*)d_in[25];
  const float* lc_W  = (const float*)d_in[26];
  const float* lc_b  = (const float*)d_in[27];
  const float* lc_g  = (const float*)d_in[28];
  const float* lc_be = (const float*)d_in[29];
  const float* act_W  = (const float*)d_in[30];
  const float* act_b  = (const float*)d_in[31];
  const float* time_W = (const float*)d_in[32];
  const float* time_b = (const float*)d_in[33];
  float* out = (float*)d_out;

  // workspace layout (~96.3 MB)
  unsigned short* xemb = (unsigned short*)d_ws;              // [1024][256][64] bf16
  unsigned short* hs   = xemb + (size_t)S_*B_*E_;            // [1023][256][128] bf16
  float* hT  = (float*)(hs + (size_t)(S_-1)*B_*H_);          // [256][128] fp32
  float* dh0 = hT  + B_*H_;
  float* dc0 = dh0 + B_*H_;

  init_kernel<<<dim3((B_*S_)/4), dim3(256), 0, stream>>>(
      x, init_W, init_b, init_g, init_be, xemb);
  lstm_kernel<<<dim3(16), dim3(512), 0, stream>>>(
      enc_Wih, enc_Whh, enc_bih, enc_bhh, xemb, S_, nullptr, nullptr, hT, nullptr);
  latent_kernel<<<dim3(B_), dim3(128), 0, stream>>>(
      hT, eps, mu_W, mu_b, mu_g, mu_be, lv_W, lv_b, lv_g, lv_be,
      lh_W, lh_b, lh_g, lh_be, lc_W, lc_b, lc_g, lc_be, out, dh0, dc0);
  lstm_kernel<<<dim3(16), dim3(512), 0, stream>>>(
      dec_Wih, dec_Whh, dec_bih, dec_bhh, xemb, S_-1, dh0, dc0, nullptr, hs);
  out_kernel<<<dim3((B_*(S_-1))/16/4), dim3(256), 0, stream>>>(
      hs, act_W, act_b, time_W, time_b, out);
}

// Round 6
// 1952.631 us; speedup vs baseline: 1.3968x; 1.3968x over previous
//
#include <hip/hip_runtime.h>
#include <hip/hip_bf16.h>

// LogVAE. R5 = R4 verbatim resubmit (4x "container failed twice"; R4 is
// hang-proof by construction: plain __syncthreads, fixed trip counts, uniform
// barriers, audited in-bounds indexing — so failures are almost certainly
// infra; if this fails again, R6 = byte-identical R0 for a conclusive test).
//  - 32 WGs x 8 batch: batches mapped to MFMA rows {0,1,4,5,8,9,12,13} so every
//    lane epilogues exactly regs r=0,1 (2 cell updates/lane, no divergence).
//  - gx = x_emb @ Wih^T + bih + bhh precomputed (bf16, swizzled for per-lane
//    dwordx4 loads) -> in-loop MFMA drops K=192 -> K=128 (16 MFMA/wave/step).
//  - Fallback (small ws): in-loop x MFMA (K=192), same mapping.

#define B_ 256
#define S_ 1024
#define NF_ 32
#define E_ 64
#define H_ 128
#define L_ 64
#define C_ 31

#define ACTS_OFF 0
#define TS_OFF   8118528   // 256*1023*31
#define MU_OFF   8380416   // + 256*1023
#define LV_OFF   8396800   // + 256*64

#define XEMB_BYTES 33554432ull    // 1024*256*64*2
#define GXS_BYTES  268435456ull   // 1024*32*8*64*8*2
#define HS_BYTES   67043328ull    // 1023*256*128*2
#define SMALL_BYTES 393216ull     // 3 * 256*128*4

typedef __attribute__((ext_vector_type(8))) short short8;
typedef __attribute__((ext_vector_type(4))) float float4v;
typedef __attribute__((ext_vector_type(4))) unsigned int uint4v;

__device__ inline unsigned short f2bf(float x){
  union { float f; unsigned u; } a; a.f = x;
  unsigned r = a.u + 0x7FFFu + ((a.u >> 16) & 1u);
  return (unsigned short)(r >> 16);
}
__device__ inline float u2f(unsigned u){ union { unsigned u; float f; } x; x.u = u; return x.f; }
__device__ inline float frcp(float x){
#if __has_builtin(__builtin_amdgcn_rcpf)
  return __builtin_amdgcn_rcpf(x);
#else
  return 1.0f / x;
#endif
}
__device__ inline float fsig(float x){ return frcp(1.0f + __expf(-x)); }
__device__ inline float ftanh(float x){ return 1.0f - 2.0f*frcp(1.0f + __expf(2.0f*x)); }
__device__ inline float leaky(float x){ return x >= 0.0f ? x : 0.01f*x; }
__device__ inline float wredsum(float v){
  v += __shfl_xor(v, 32, 64);
  v += __shfl_xor(v, 16, 64);
  v += __shfl_xor(v,  8, 64);
  v += __shfl_xor(v,  4, 64);
  v += __shfl_xor(v,  2, 64);
  v += __shfl_xor(v,  1, 64);
  return v;
}

// ---------------- Kernel A: x_emb = LN(leaky(x @ W.T + b)) -> bf16 [S][B][E] --
__global__ __launch_bounds__(256) void init_kernel(
    const float* __restrict__ x, const float* __restrict__ W,
    const float* __restrict__ bias, const float* __restrict__ gam,
    const float* __restrict__ beta, unsigned short* __restrict__ xemb)
{
  const int wave = threadIdx.x >> 6, lane = threadIdx.x & 63;
  const int r = blockIdx.x * 4 + wave;        // r = b*S + s (matches x layout)
  const int b = r >> 10, s = r & 1023;
  const float* xr = x + (size_t)r * NF_;
  float xv = (lane < NF_) ? xr[lane] : 0.0f;
  float acc = bias[lane];
  const float* wr = W + lane * NF_;
  #pragma unroll
  for (int k = 0; k < NF_; ++k)
    acc += __shfl(xv, k, 64) * wr[k];
  acc = leaky(acc);
  float m = wredsum(acc) * (1.0f/64.0f);
  float d = acc - m;
  float v = wredsum(d*d) * (1.0f/64.0f);
  float y = d * rsqrtf(v + 1e-5f) * gam[lane] + beta[lane];
  xemb[((size_t)s * B_ + b) * E_ + lane] = f2bf(y);   // [S][B][E]
}

// ---------------- Kernel A2: gx = xemb @ Wih^T + bih + bhh, bf16 swizzled ----
// gxs layout: [t][wgb][w][lane][8 shorts = (g0rp0,g0rp1,g1rp0,...,g3rp1)]
// where consumer lane = q*16+c16 holds (batch wgb*8+2q+rp, gate g*128+16w+c16).
__global__ __launch_bounds__(512, 2) void gx_kernel(
    const unsigned short* __restrict__ xemb, const float* __restrict__ Wih,
    const float* __restrict__ bih, const float* __restrict__ bhh,
    unsigned short* __restrict__ gxs)
{
  const int tid = threadIdx.x;
  const int w = tid >> 6, lane = tid & 63;
  const int q = lane >> 4, c16 = lane & 15;
  const int wgb = blockIdx.x & 31, tblk = blockIdx.x >> 5;

  short8 Bf[4][2]; float bias[4];
  #pragma unroll
  for (int g = 0; g < 4; ++g){
    const int gcol = g*128 + w*16 + c16;
    bias[g] = bih[gcol] + bhh[gcol];
    #pragma unroll
    for (int kb = 0; kb < 2; ++kb){
      union { short8 v; unsigned short u[8]; } tmp;
      #pragma unroll
      for (int j = 0; j < 8; ++j)
        tmp.u[j] = f2bf(Wih[gcol*E_ + kb*32 + q*8 + j]);
      Bf[g][kb] = tmp.v;
    }
  }
  const int tl = c16 >> 3, bb = c16 & 7;   // A row m=c16 -> (tlocal, batch)
  for (int mt = 0; mt < 16; ++mt){
    const int tpair = tblk*32 + mt*2;
    const unsigned short* ap = xemb + (((size_t)(tpair + tl))*B_ + wgb*8 + bb)*E_ + q*8;
    short8 a0 = *(const short8*)ap;
    short8 a1 = *(const short8*)(ap + 32);
    float4v acc[4];
    #pragma unroll
    for (int g = 0; g < 4; ++g){
      acc[g] = (float4v){bias[g], bias[g], bias[g], bias[g]};
      acc[g] = __builtin_amdgcn_mfma_f32_16x16x32_bf16(a0, Bf[g][0], acc[g], 0, 0, 0);
      acc[g] = __builtin_amdgcn_mfma_f32_16x16x32_bf16(a1, Bf[g][1], acc[g], 0, 0, 0);
    }
    // reg (g,r): m = 4q+r -> t = tpair + (q>>1), bb = 4(q&1)+r
    const int t = tpair + (q >> 1);
    size_t base = ((((size_t)t*32 + wgb)*8 + w)*64 + (2*(q&1))*16 + c16); // uint4 idx
    unsigned p1[4], p2[4];
    #pragma unroll
    for (int g = 0; g < 4; ++g){
      p1[g] = ((unsigned)f2bf(acc[g][1]) << 16) | f2bf(acc[g][0]); // r=0,1 -> bb even pair
      p2[g] = ((unsigned)f2bf(acc[g][3]) << 16) | f2bf(acc[g][2]); // r=2,3 -> bb odd pair
    }
    *(uint4v*)(gxs + base*8)        = *(uint4v*)p1;
    *(uint4v*)(gxs + (base+16)*8)   = *(uint4v*)p2;
  }
}

// ---------------- Kernel B: LSTM recurrence ---------------------------------
// grid=32 (8 batch/WG), block=512. Wave w owns gates of hidden [16w,16w+16).
// Batch bb -> MFMA row m = 4*(bb>>1) + (bb&1); rows with m%4>=2 stay zero.
template<bool USE_GX>
__global__ __launch_bounds__(512, 2) void lstm_kernel(
    const float* __restrict__ Wih,   // [512][64]  (fallback only)
    const float* __restrict__ Whh,   // [512][128]
    const float* __restrict__ bih, const float* __restrict__ bhh, // fallback only
    const unsigned short* __restrict__ xemb,  // fallback only
    const unsigned short* __restrict__ gxs,   // USE_GX only
    int T,
    const float* __restrict__ h0, const float* __restrict__ c0, // null => ones/zeros
    float* __restrict__ hT_out,               // [256][128] fp32 or null
    unsigned short* __restrict__ hs_out)      // [T][256][128] bf16 or null
{
  constexpr int KB = USE_GX ? 4 : 6;
  __shared__ unsigned short hbuf[2][16*136];
  const int tid = threadIdx.x;
  const int wave = tid >> 6, lane = tid & 63;
  const int q = lane >> 4, c16 = lane & 15;
  const int bt0 = blockIdx.x * 8;
  const int hu = wave * 16 + c16;

  short8 Bf[4][KB];
  float bias[4];
  #pragma unroll
  for (int g = 0; g < 4; ++g){
    const int gcol = g*128 + hu;
    if (!USE_GX) bias[g] = bih[gcol] + bhh[gcol];
    #pragma unroll
    for (int kb = 0; kb < KB; ++kb){
      union { short8 v; unsigned short u[8]; } tmp;
      #pragma unroll
      for (int j = 0; j < 8; ++j){
        int k = kb*32 + q*8 + j;
        float wv = (kb < 4) ? Whh[gcol*H_ + k] : Wih[gcol*E_ + (k - H_)];
        tmp.u[j] = f2bf(wv);
      }
      Bf[g][kb] = tmp.v;
    }
  }

  // LDS init: zero both buffers, then fill valid rows of buf0.
  unsigned short* hflat = &hbuf[0][0];
  for (int idx = tid; idx < 2*16*136; idx += 512) hflat[idx] = 0;
  __syncthreads();
  for (int idx = tid; idx < 16*H_; idx += 512){
    int m = idx >> 7, k = idx & 127;
    if ((m & 3) < 2){
      int bb = 2*(m >> 2) + (m & 1);
      hbuf[0][m*136 + k] = h0 ? f2bf(h0[((size_t)(bt0 + bb))*H_ + k])
                              : (unsigned short)0x3F80; // bf16(1.0)
    }
  }
  float cst[2];
  #pragma unroll
  for (int rp = 0; rp < 2; ++rp)
    cst[rp] = c0 ? c0[((size_t)(bt0 + 2*q + rp))*H_ + hu] : 0.0f;
  __syncthreads();

  // prefetch (gx: depth 2; x: depth 1)
  const uint4v* gq = (const uint4v*)gxs;
  size_t gbase = 0; uint4v g0, g1;
  short8 xf0, xf1;
  int bbx = 0;
  if (USE_GX){
    gbase = (((size_t)blockIdx.x)*8 + wave)*64 + lane;
    g0 = gq[gbase];
    int t1 = (T > 1) ? 1 : 0;
    g1 = gq[gbase + (size_t)t1 * 16384];
  } else {
    bbx = 2*(c16 >> 2) + (c16 & 1);   // dup for invalid rows (harmless)
    const unsigned short* xp = xemb + ((size_t)(bt0 + bbx))*E_ + q*8;
    xf0 = *(const short8*)xp; xf1 = *(const short8*)(xp + 32);
  }

  for (int t = 0; t < T; ++t){
    const int cur = t & 1;
    const unsigned short* hb = hflat + cur*2176;
    short8 Af[4];
    #pragma unroll
    for (int kb = 0; kb < 4; ++kb)
      Af[kb] = *(const short8*)(hb + c16*136 + kb*32 + q*8);

    uint4v g2; short8 nx0, nx1;
    if (USE_GX){
      int t2 = (t + 2 < T) ? t + 2 : T - 1;
      g2 = gq[gbase + (size_t)t2 * 16384];
    } else {
      int t1 = (t + 1 < T) ? t + 1 : t;
      const unsigned short* xp = xemb + ((size_t)t1*B_ + bt0 + bbx)*E_ + q*8;
      nx0 = *(const short8*)xp; nx1 = *(const short8*)(xp + 32);
    }

    float4v acc[4];
    if (USE_GX){
      unsigned d[4] = {g0.x, g0.y, g0.z, g0.w};
      #pragma unroll
      for (int g = 0; g < 4; ++g){
        float lo = u2f(d[g] << 16);
        float hi = u2f(d[g] & 0xFFFF0000u);
        acc[g] = (float4v){lo, hi, lo, hi};
      }
    } else {
      #pragma unroll
      for (int g = 0; g < 4; ++g)
        acc[g] = (float4v){bias[g], bias[g], bias[g], bias[g]};
    }
    #pragma unroll
    for (int kb = 0; kb < 4; ++kb){
      #pragma unroll
      for (int g = 0; g < 4; ++g)
        acc[g] = __builtin_amdgcn_mfma_f32_16x16x32_bf16(Af[kb], Bf[g][kb], acc[g], 0, 0, 0);
    }
    if (!USE_GX){
      #pragma unroll
      for (int g = 0; g < 4; ++g){
        acc[g] = __builtin_amdgcn_mfma_f32_16x16x32_bf16(xf0, Bf[g][4], acc[g], 0, 0, 0);
        acc[g] = __builtin_amdgcn_mfma_f32_16x16x32_bf16(xf1, Bf[g][5], acc[g], 0, 0, 0);
      }
    }

    unsigned short* hw = hflat + (1 - cur)*2176;
    #pragma unroll
    for (int rp = 0; rp < 2; ++rp){
      float ig = fsig(acc[0][rp]);
      float fg = fsig(acc[1][rp]);
      float gg = ftanh(acc[2][rp]);
      float og = fsig(acc[3][rp]);
      float cn = fg*cst[rp] + ig*gg;
      cst[rp] = cn;
      float hn = og * ftanh(cn);
      unsigned short hb16 = f2bf(hn);
      hw[(4*q + rp)*136 + hu] = hb16;
      if (hs_out) hs_out[((size_t)t*B_ + bt0 + 2*q + rp)*H_ + hu] = hb16;
      if (hT_out && t == T-1) hT_out[((size_t)(bt0 + 2*q + rp))*H_ + hu] = hn;
    }
    if (USE_GX){ g0 = g1; g1 = g2; } else { xf0 = nx0; xf1 = nx1; }
    __syncthreads();
  }
}

// ---------------- Kernel C: mu/logvar/latent/dh0/dc0 ------------------------
__global__ __launch_bounds__(128) void latent_kernel(
    const float* __restrict__ hT, const float* __restrict__ eps,
    const float* __restrict__ mu_W, const float* __restrict__ mu_b,
    const float* __restrict__ mu_g, const float* __restrict__ mu_be,
    const float* __restrict__ lv_W, const float* __restrict__ lv_b,
    const float* __restrict__ lv_g, const float* __restrict__ lv_be,
    const float* __restrict__ lh_W, const float* __restrict__ lh_b,
    const float* __restrict__ lh_g, const float* __restrict__ lh_be,
    const float* __restrict__ lc_W, const float* __restrict__ lc_b,
    const float* __restrict__ lc_g, const float* __restrict__ lc_be,
    float* __restrict__ out, float* __restrict__ dh0, float* __restrict__ dc0)
{
  const int b = blockIdx.x, tid = threadIdx.x;
  const int wave = tid >> 6, lane = tid & 63;
  __shared__ float shT[H_];
  __shared__ float smu[L_], slv[L_], slat[L_];
  __shared__ float part[2];
  shT[tid] = hT[(size_t)b*H_ + tid];
  __syncthreads();
  {
    const float* W = wave ? lv_W : mu_W;
    float a = (wave ? lv_b : mu_b)[lane];
    for (int k = 0; k < H_; ++k) a += shT[k] * W[lane*H_ + k];
    a = leaky(a);
    float m = wredsum(a) * (1.0f/L_);
    float d = a - m;
    float v = wredsum(d*d) * (1.0f/L_);
    float y = d * rsqrtf(v + 1e-5f) * (wave ? lv_g : mu_g)[lane] + (wave ? lv_be : mu_be)[lane];
    out[(wave ? LV_OFF : MU_OFF) + (size_t)b*L_ + lane] = y;
    if (wave) slv[lane] = y; else smu[lane] = y;
  }
  __syncthreads();
  if (tid < L_) slat[tid] = smu[tid] + eps[(size_t)b*L_ + tid] * __expf(0.5f*slv[tid]);
  __syncthreads();
  #pragma unroll 1
  for (int which = 0; which < 2; ++which){
    const float* W = which ? lc_W : lh_W;
    float p = (which ? lc_b : lh_b)[tid];
    for (int k = 0; k < L_; ++k) p += slat[k] * W[tid*L_ + k];
    p = leaky(p);
    float s = wredsum(p);
    if (lane == 0) part[wave] = s;
    __syncthreads();
    float mean = (part[0] + part[1]) * (1.0f/H_);
    __syncthreads();
    float d = p - mean;
    float s2 = wredsum(d*d);
    if (lane == 0) part[wave] = s2;
    __syncthreads();
    float var = (part[0] + part[1]) * (1.0f/H_);
    __syncthreads();
    float y = d * rsqrtf(var + 1e-5f) * (which ? lc_g : lh_g)[tid] + (which ? lc_be : lh_be)[tid];
    (which ? dc0 : dh0)[(size_t)b*H_ + tid] = y;
  }
}

// ---------------- Kernel D: acts/ts heads via MFMA (N=32: 31 acts + ts) -----
__global__ __launch_bounds__(256) void out_kernel(
    const unsigned short* __restrict__ hs,   // [1023][256][128] bf16
    const float* __restrict__ actW, const float* __restrict__ actB,
    const float* __restrict__ timeW, const float* __restrict__ timeB,
    float* __restrict__ out)
{
  const int wave = threadIdx.x >> 6, lane = threadIdx.x & 63;
  const int quad = lane >> 4, c16 = lane & 15;
  const int mt = blockIdx.x * 4 + wave;      // M-tile of 16 rows (r = t*256 + b)
  short8 Wf[2][4]; float biasn[2];
  #pragma unroll
  for (int ti = 0; ti < 2; ++ti){
    const int n = ti*16 + c16;
    biasn[ti] = (n < C_) ? actB[n] : timeB[0];
    #pragma unroll
    for (int kb = 0; kb < 4; ++kb){
      union { short8 v; unsigned short u[8]; } tmp;
      #pragma unroll
      for (int j = 0; j < 8; ++j){
        int k = kb*32 + quad*8 + j;
        tmp.u[j] = f2bf((n < C_) ? actW[n*H_ + k] : timeW[k]);
      }
      Wf[ti][kb] = tmp.v;
    }
  }
  const unsigned short* hp = hs + ((size_t)mt*16 + c16)*H_ + quad*8;
  float4v acc[2];
  #pragma unroll
  for (int ti = 0; ti < 2; ++ti) acc[ti] = (float4v){biasn[ti], biasn[ti], biasn[ti], biasn[ti]};
  #pragma unroll
  for (int kb = 0; kb < 4; ++kb){
    short8 a = *(const short8*)(hp + kb*32);
    acc[0] = __builtin_amdgcn_mfma_f32_16x16x32_bf16(a, Wf[0][kb], acc[0], 0, 0, 0);
    acc[1] = __builtin_amdgcn_mfma_f32_16x16x32_bf16(a, Wf[1][kb], acc[1], 0, 0, 0);
  }
  #pragma unroll
  for (int ti = 0; ti < 2; ++ti){
    const int n = ti*16 + c16;
    #pragma unroll
    for (int r = 0; r < 4; ++r){
      int rr = mt*16 + quad*4 + r;
      int tt = rr >> 8, b = rr & 255;
      float v = acc[ti][r];
      if (n < C_) out[ACTS_OFF + ((size_t)b*1023 + tt)*C_ + n] = v;
      else        out[TS_OFF + (size_t)b*1023 + tt] = v;
    }
  }
}

// ---------------- launch ----------------------------------------------------
extern "C" void kernel_launch(void* const* d_in, const int* in_sizes, int n_in,
                              void* d_out, int out_size, void* d_ws, size_t ws_size,
                              hipStream_t stream)
{
  (void)in_sizes; (void)n_in; (void)out_size;
  const float* x       = (const float*)d_in[0];
  const float* eps     = (const float*)d_in[1];
  const float* init_W  = (const float*)d_in[2];
  const float* init_b  = (const float*)d_in[3];
  const float* init_g  = (const float*)d_in[4];
  const float* init_be = (const float*)d_in[5];
  const float* enc_Wih = (const float*)d_in[6];
  const float* enc_Whh = (const float*)d_in[7];
  const float* enc_bih = (const float*)d_in[8];
  const float* enc_bhh = (const float*)d_in[9];
  const float* mu_W  = (const float*)d_in[10];
  const float* mu_b  = (const float*)d_in[11];
  const float* mu_g  = (const float*)d_in[12];
  const float* mu_be = (const float*)d_in[13];
  const float* lv_W  = (const float*)d_in[14];
  const float* lv_b  = (const float*)d_in[15];
  const float* lv_g  = (const float*)d_in[16];
  const float* lv_be = (const float*)d_in[17];
  const float* dec_Wih = (const float*)d_in[18];
  const float* dec_Whh = (const float*)d_in[19];
  const float* dec_bih = (const float*)d_in[20];
  const float* dec_bhh = (const float*)d_in[21];
  const float* lh_W  = (const float*)d_in[22];
  const float* lh_b  = (const float*)d_in[23];
  const float* lh_g  = (const float*)d_in[24];
  const float* lh_be = (const float*)d_in[25];
  const float* lc_W  = (const float*)d_in[26];
  const float* lc_b  = (const float*)d_in[27];
  const float* lc_g  = (const float*)d_in[28];
  const float* lc_be = (const float*)d_in[29];
  const float* act_W  = (const float*)d_in[30];
  const float* act_b  = (const float*)d_in[31];
  const float* time_W = (const float*)d_in[32];
  const float* time_b = (const float*)d_in[33];
  float* out = (float*)d_out;

  const bool use_gx = ws_size >= (XEMB_BYTES + GXS_BYTES + HS_BYTES + SMALL_BYTES);

  unsigned short* xemb = (unsigned short*)d_ws;
  unsigned short* gxs  = xemb + XEMB_BYTES/2;   // gx path only
  unsigned short* hs   = use_gx ? (gxs + GXS_BYTES/2) : (xemb + XEMB_BYTES/2);
  float* hT  = (float*)(hs + HS_BYTES/2);
  float* dh0 = hT  + B_*H_;
  float* dc0 = dh0 + B_*H_;

  init_kernel<<<dim3((B_*S_)/4), dim3(256), 0, stream>>>(
      x, init_W, init_b, init_g, init_be, xemb);

  if (use_gx){
    gx_kernel<<<dim3(1024), dim3(512), 0, stream>>>(xemb, enc_Wih, enc_bih, enc_bhh, gxs);
    lstm_kernel<true><<<dim3(32), dim3(512), 0, stream>>>(
        nullptr, enc_Whh, nullptr, nullptr, nullptr, gxs, S_,
        nullptr, nullptr, hT, nullptr);
  } else {
    lstm_kernel<false><<<dim3(32), dim3(512), 0, stream>>>(
        enc_Wih, enc_Whh, enc_bih, enc_bhh, xemb, nullptr, S_,
        nullptr, nullptr, hT, nullptr);
  }

  latent_kernel<<<dim3(B_), dim3(128), 0, stream>>>(
      hT, eps, mu_W, mu_b, mu_g, mu_be, lv_W, lv_b, lv_g, lv_be,
      lh_W, lh_b, lh_g, lh_be, lc_W, lc_b, lc_g, lc_be, out, dh0, dc0);

  if (use_gx){
    gx_kernel<<<dim3(1024), dim3(512), 0, stream>>>(xemb, dec_Wih, dec_bih, dec_bhh, gxs);
    lstm_kernel<true><<<dim3(32), dim3(512), 0, stream>>>(
        nullptr, dec_Whh, nullptr, nullptr, nullptr, gxs, S_-1,
        dh0, dc0, nullptr, hs);
  } else {
    lstm_kernel<false><<<dim3(32), dim3(512), 0, stream>>>(
        dec_Wih, dec_Whh, dec_bih, dec_bhh, xemb, nullptr, S_-1,
        dh0, dc0, nullptr, hs);
  }

  out_kernel<<<dim3((B_*(S_-1))/16/4), dim3(256), 0, stream>>>(
      hs, act_W, act_b, time_W, time_b, out);
}

// Round 7
// 1574.510 us; speedup vs baseline: 1.7322x; 1.2402x over previous
//
#include <hip/hip_runtime.h>
#include <hip/hip_bf16.h>

// LogVAE. R6: recurrence spread to 64 WGs x 4 batch (rows {0,4,8,12} -> exactly
// 1 cell/lane), in-loop x MFMA (K=192; the 268MB gx buffer does NOT fit ws —
// R5 FETCH=18MB proved the fallback ran), shared-rcp gate math, zero-pad
// stride-0 x prefetch for non-batch lanes. __syncthreads kept (barrier swap
// is next round's isolated experiment).

#define B_ 256
#define S_ 1024
#define NF_ 32
#define E_ 64
#define H_ 128
#define L_ 64
#define C_ 31

#define ACTS_OFF 0
#define TS_OFF   8118528   // 256*1023*31
#define MU_OFF   8380416   // + 256*1023
#define LV_OFF   8396800   // + 256*64

#define LOG2E  1.44269504f
#define LOG2E2 2.88539008f

typedef __attribute__((ext_vector_type(8))) short short8;
typedef __attribute__((ext_vector_type(4))) float float4v;

__device__ inline unsigned short f2bf(float x){
  union { float f; unsigned u; } a; a.f = x;
  unsigned r = a.u + 0x7FFFu + ((a.u >> 16) & 1u);
  return (unsigned short)(r >> 16);
}
__device__ inline float frcp(float x){
#if __has_builtin(__builtin_amdgcn_rcpf)
  return __builtin_amdgcn_rcpf(x);
#else
  return 1.0f / x;
#endif
}
__device__ inline float fexp2(float x){
#if __has_builtin(__builtin_amdgcn_exp2f)
  return __builtin_amdgcn_exp2f(x);
#else
  return exp2f(x);
#endif
}
__device__ inline float fsig(float x){ return frcp(1.0f + fexp2(-LOG2E*x)); }
__device__ inline float leaky(float x){ return x >= 0.0f ? x : 0.01f*x; }
__device__ inline float wredsum(float v){
  v += __shfl_xor(v, 32, 64);
  v += __shfl_xor(v, 16, 64);
  v += __shfl_xor(v,  8, 64);
  v += __shfl_xor(v,  4, 64);
  v += __shfl_xor(v,  2, 64);
  v += __shfl_xor(v,  1, 64);
  return v;
}

// ---------------- Kernel A: x_emb = LN(leaky(x @ W.T + b)) -> bf16 [S][B][E] --
__global__ __launch_bounds__(256) void init_kernel(
    const float* __restrict__ x, const float* __restrict__ W,
    const float* __restrict__ bias, const float* __restrict__ gam,
    const float* __restrict__ beta, unsigned short* __restrict__ xemb)
{
  // zero the 64-short pad after xemb (stride-0 x-load target for non-batch lanes)
  if (blockIdx.x == 0 && threadIdx.x < 64)
    xemb[(size_t)S_*B_*E_ + threadIdx.x] = 0;

  const int wave = threadIdx.x >> 6, lane = threadIdx.x & 63;
  const int r = blockIdx.x * 4 + wave;        // r = b*S + s (matches x layout)
  const int b = r >> 10, s = r & 1023;
  const float* xr = x + (size_t)r * NF_;
  float xv = (lane < NF_) ? xr[lane] : 0.0f;
  float acc = bias[lane];
  const float* wr = W + lane * NF_;
  #pragma unroll
  for (int k = 0; k < NF_; ++k)
    acc += __shfl(xv, k, 64) * wr[k];
  acc = leaky(acc);
  float m = wredsum(acc) * (1.0f/64.0f);
  float d = acc - m;
  float v = wredsum(d*d) * (1.0f/64.0f);
  float y = d * rsqrtf(v + 1e-5f) * gam[lane] + beta[lane];
  xemb[((size_t)s * B_ + b) * E_ + lane] = f2bf(y);   // [S][B][E]
}

// ---------------- Kernel B: LSTM recurrence ---------------------------------
// grid=64 (4 batch/WG), block=512 (8 waves). Wave w owns i,f,g,o gates of
// hidden [16w,16w+16). Batch b_local -> MFMA row 4*b_local; lane (q,c16)
// epilogues exactly reg r=0 (cell = batch q, hidden unit 16w+c16).
__global__ __launch_bounds__(512, 2) void lstm_kernel(
    const float* __restrict__ Wih,   // [512][64]
    const float* __restrict__ Whh,   // [512][128]
    const float* __restrict__ bih, const float* __restrict__ bhh,
    const unsigned short* __restrict__ xemb,  // [S][256][64] bf16 (+64 zero pad)
    int T,
    const float* __restrict__ h0, const float* __restrict__ c0, // null => ones/zeros
    float* __restrict__ hT_out,               // [256][128] fp32 or null
    unsigned short* __restrict__ hs_out)      // [T][256][128] bf16 or null
{
  __shared__ unsigned short hbuf[2][16*136];  // +8 pad/row
  const int tid = threadIdx.x;
  const int wave = tid >> 6, lane = tid & 63;
  const int q = lane >> 4, c16 = lane & 15;
  const int bt0 = blockIdx.x * 4;
  const int hu = wave * 16 + c16;

  // Persistent B frags: kb 0..3 = Whh (K=0..128), kb 4..5 = Wih (K=128..192)
  short8 Bf[4][6];
  float bias[4];
  #pragma unroll
  for (int g = 0; g < 4; ++g){
    const int gcol = g*128 + hu;
    bias[g] = bih[gcol] + bhh[gcol];
    #pragma unroll
    for (int kb = 0; kb < 6; ++kb){
      union { short8 v; unsigned short u[8]; } tmp;
      #pragma unroll
      for (int j = 0; j < 8; ++j){
        int k = kb*32 + q*8 + j;
        float wv = (kb < 4) ? Whh[gcol*H_ + k] : Wih[gcol*E_ + (k - H_)];
        tmp.u[j] = f2bf(wv);
      }
      Bf[g][kb] = tmp.v;
    }
  }

  // LDS: zero both buffers, then fill rows {0,4,8,12} of buf0 with h0.
  unsigned short* hflat = &hbuf[0][0];
  for (int idx = tid; idx < 2*16*136; idx += 512) hflat[idx] = 0;
  __syncthreads();
  {
    int b = tid >> 7, k = tid & 127;   // tid < 512 = 4*128
    hbuf[0][(4*b)*136 + k] = h0 ? f2bf(h0[((size_t)(bt0 + b))*H_ + k])
                                : (unsigned short)0x3F80; // bf16(1.0)
  }
  float cst = c0 ? c0[((size_t)(bt0 + q))*H_ + hu] : 0.0f;
  __syncthreads();

  // x prefetch: lanes c16%4==0 carry batch c16>>2; others read the zero pad
  // with stride 0 (no per-step re-zeroing, no divergent branch).
  const int is_x = ((c16 & 3) == 0);
  const unsigned short* xp = is_x
      ? (xemb + ((size_t)(bt0 + (c16 >> 2)))*E_ + q*8)
      : (xemb + (size_t)S_*B_*E_ + q*8);
  const size_t xstep = is_x ? (size_t)B_*E_ : 0;
  short8 xf0 = *(const short8*)xp;
  short8 xf1 = *(const short8*)(xp + 32);
  xp += xstep;   // -> t=1

  for (int t = 0; t < T; ++t){
    const int cur = t & 1;
    const unsigned short* hb = hflat + cur*2176;
    short8 Af[4];
    #pragma unroll
    for (int kb = 0; kb < 4; ++kb)
      Af[kb] = *(const short8*)(hb + c16*136 + kb*32 + q*8);

    // prefetch x for t+1 (clamped)
    short8 nx0 = *(const short8*)xp;
    short8 nx1 = *(const short8*)(xp + 32);
    if (t + 2 < T) xp += xstep;

    float4v acc[4];
    #pragma unroll
    for (int g = 0; g < 4; ++g)
      acc[g] = (float4v){bias[g], 0.0f, 0.0f, 0.0f};
    #pragma unroll
    for (int kb = 0; kb < 4; ++kb){
      #pragma unroll
      for (int g = 0; g < 4; ++g)
        acc[g] = __builtin_amdgcn_mfma_f32_16x16x32_bf16(Af[kb], Bf[g][kb], acc[g], 0, 0, 0);
    }
    #pragma unroll
    for (int g = 0; g < 4; ++g){
      acc[g] = __builtin_amdgcn_mfma_f32_16x16x32_bf16(xf0, Bf[g][4], acc[g], 0, 0, 0);
      acc[g] = __builtin_amdgcn_mfma_f32_16x16x32_bf16(xf1, Bf[g][5], acc[g], 0, 0, 0);
    }

    // epilogue: 1 cell/lane (reg r=0). Shared-rcp pairs:
    // sig(i)*tanh(g) = e^i(e^2g-1) / [(1+e^i)(1+e^2g)], same for o/c.
    float gi = acc[0][0], gf = acc[1][0], gg = acc[2][0], go = acc[3][0];
    float ei  = fexp2(gi * LOG2E);
    float e2g = fexp2(gg * LOG2E2);
    float t1  = (ei * (e2g - 1.0f)) * frcp((1.0f + ei) * (1.0f + e2g));
    float sf  = fsig(gf);
    float c   = fmaf(sf, cst, t1);
    cst = c;
    float eo  = fexp2(go * LOG2E);
    float e2c = fexp2(fminf(c * LOG2E2, 126.0f));   // clamp: c can accumulate
    float h   = (eo * (e2c - 1.0f)) * frcp((1.0f + eo) * (1.0f + e2c));

    unsigned short* hw = hflat + (1 - cur)*2176;
    unsigned short hb16 = f2bf(h);
    hw[(4*q)*136 + hu] = hb16;
    if (hs_out) hs_out[((size_t)t*B_ + bt0 + q)*H_ + hu] = hb16;
    if (hT_out && t == T-1) hT_out[((size_t)(bt0 + q))*H_ + hu] = h;
    xf0 = nx0; xf1 = nx1;
    __syncthreads();
  }
}

// ---------------- Kernel C: mu/logvar/latent/dh0/dc0 ------------------------
__global__ __launch_bounds__(128) void latent_kernel(
    const float* __restrict__ hT, const float* __restrict__ eps,
    const float* __restrict__ mu_W, const float* __restrict__ mu_b,
    const float* __restrict__ mu_g, const float* __restrict__ mu_be,
    const float* __restrict__ lv_W, const float* __restrict__ lv_b,
    const float* __restrict__ lv_g, const float* __restrict__ lv_be,
    const float* __restrict__ lh_W, const float* __restrict__ lh_b,
    const float* __restrict__ lh_g, const float* __restrict__ lh_be,
    const float* __restrict__ lc_W, const float* __restrict__ lc_b,
    const float* __restrict__ lc_g, const float* __restrict__ lc_be,
    float* __restrict__ out, float* __restrict__ dh0, float* __restrict__ dc0)
{
  const int b = blockIdx.x, tid = threadIdx.x;
  const int wave = tid >> 6, lane = tid & 63;
  __shared__ float shT[H_];
  __shared__ float smu[L_], slv[L_], slat[L_];
  __shared__ float part[2];
  shT[tid] = hT[(size_t)b*H_ + tid];
  __syncthreads();
  {
    const float* W = wave ? lv_W : mu_W;
    float a = (wave ? lv_b : mu_b)[lane];
    for (int k = 0; k < H_; ++k) a += shT[k] * W[lane*H_ + k];
    a = leaky(a);
    float m = wredsum(a) * (1.0f/L_);
    float d = a - m;
    float v = wredsum(d*d) * (1.0f/L_);
    float y = d * rsqrtf(v + 1e-5f) * (wave ? lv_g : mu_g)[lane] + (wave ? lv_be : mu_be)[lane];
    out[(wave ? LV_OFF : MU_OFF) + (size_t)b*L_ + lane] = y;
    if (wave) slv[lane] = y; else smu[lane] = y;
  }
  __syncthreads();
  if (tid < L_) slat[tid] = smu[tid] + eps[(size_t)b*L_ + tid] * expf(0.5f*slv[tid]);
  __syncthreads();
  #pragma unroll 1
  for (int which = 0; which < 2; ++which){
    const float* W = which ? lc_W : lh_W;
    float p = (which ? lc_b : lh_b)[tid];
    for (int k = 0; k < L_; ++k) p += slat[k] * W[tid*L_ + k];
    p = leaky(p);
    float s = wredsum(p);
    if (lane == 0) part[wave] = s;
    __syncthreads();
    float mean = (part[0] + part[1]) * (1.0f/H_);
    __syncthreads();
    float d = p - mean;
    float s2 = wredsum(d*d);
    if (lane == 0) part[wave] = s2;
    __syncthreads();
    float var = (part[0] + part[1]) * (1.0f/H_);
    __syncthreads();
    float y = d * rsqrtf(var + 1e-5f) * (which ? lc_g : lh_g)[tid] + (which ? lc_be : lh_be)[tid];
    (which ? dc0 : dh0)[(size_t)b*H_ + tid] = y;
  }
}

// ---------------- Kernel D: acts/ts heads via MFMA (N=32: 31 acts + ts) -----
__global__ __launch_bounds__(256) void out_kernel(
    const unsigned short* __restrict__ hs,   // [1023][256][128] bf16
    const float* __restrict__ actW, const float* __restrict__ actB,
    const float* __restrict__ timeW, const float* __restrict__ timeB,
    float* __restrict__ out)
{
  const int wave = threadIdx.x >> 6, lane = threadIdx.x & 63;
  const int quad = lane >> 4, c16 = lane & 15;
  const int mt = blockIdx.x * 4 + wave;      // M-tile of 16 rows (r = t*256 + b)
  short8 Wf[2][4]; float biasn[2];
  #pragma unroll
  for (int ti = 0; ti < 2; ++ti){
    const int n = ti*16 + c16;
    biasn[ti] = (n < C_) ? actB[n] : timeB[0];
    #pragma unroll
    for (int kb = 0; kb < 4; ++kb){
      union { short8 v; unsigned short u[8]; } tmp;
      #pragma unroll
      for (int j = 0; j < 8; ++j){
        int k = kb*32 + quad*8 + j;
        tmp.u[j] = f2bf((n < C_) ? actW[n*H_ + k] : timeW[k]);
      }
      Wf[ti][kb] = tmp.v;
    }
  }
  const unsigned short* hp = hs + ((size_t)mt*16 + c16)*H_ + quad*8;
  float4v acc[2];
  #pragma unroll
  for (int ti = 0; ti < 2; ++ti) acc[ti] = (float4v){biasn[ti], biasn[ti], biasn[ti], biasn[ti]};
  #pragma unroll
  for (int kb = 0; kb < 4; ++kb){
    short8 a = *(const short8*)(hp + kb*32);
    acc[0] = __builtin_amdgcn_mfma_f32_16x16x32_bf16(a, Wf[0][kb], acc[0], 0, 0, 0);
    acc[1] = __builtin_amdgcn_mfma_f32_16x16x32_bf16(a, Wf[1][kb], acc[1], 0, 0, 0);
  }
  #pragma unroll
  for (int ti = 0; ti < 2; ++ti){
    const int n = ti*16 + c16;
    #pragma unroll
    for (int r = 0; r < 4; ++r){
      int rr = mt*16 + quad*4 + r;
      int tt = rr >> 8, b = rr & 255;
      float v = acc[ti][r];
      if (n < C_) out[ACTS_OFF + ((size_t)b*1023 + tt)*C_ + n] = v;
      else        out[TS_OFF + (size_t)b*1023 + tt] = v;
    }
  }
}

// ---------------- launch ----------------------------------------------------
extern "C" void kernel_launch(void* const* d_in, const int* in_sizes, int n_in,
                              void* d_out, int out_size, void* d_ws, size_t ws_size,
                              hipStream_t stream)
{
  (void)in_sizes; (void)n_in; (void)out_size; (void)ws_size;
  const float* x       = (const float*)d_in[0];
  const float* eps     = (const float*)d_in[1];
  const float* init_W  = (const float*)d_in[2];
  const float* init_b  = (const float*)d_in[3];
  const float* init_g  = (const float*)d_in[4];
  const float* init_be = (const float*)d_in[5];
  const float* enc_Wih = (const float*)d_in[6];
  const float* enc_Whh = (const float*)d_in[7];
  const float* enc_bih = (const float*)d_in[8];
  const float* enc_bhh = (const float*)d_in[9];
  const float* mu_W  = (const float*)d_in[10];
  const float* mu_b  = (const float*)d_in[11];
  const float* mu_g  = (const float*)d_in[12];
  const float* mu_be = (const float*)d_in[13];
  const float* lv_W  = (const float*)d_in[14];
  const float* lv_b  = (const float*)d_in[15];
  const float* lv_g  = (const float*)d_in[16];
  const float* lv_be = (const float*)d_in[17];
  const float* dec_Wih = (const float*)d_in[18];
  const float* dec_Whh = (const float*)d_in[19];
  const float* dec_bih = (const float*)d_in[20];
  const float* dec_bhh = (const float*)d_in[21];
  const float* lh_W  = (const float*)d_in[22];
  const float* lh_b  = (const float*)d_in[23];
  const float* lh_g  = (const float*)d_in[24];
  const float* lh_be = (const float*)d_in[25];
  const float* lc_W  = (const float*)d_in[26];
  const float* lc_b  = (const float*)d_in[27];
  const float* lc_g  = (const float*)d_in[28];
  const float* lc_be = (const float*)d_in[29];
  const float* act_W  = (const float*)d_in[30];
  const float* act_b  = (const float*)d_in[31];
  const float* time_W = (const float*)d_in[32];
  const float* time_b = (const float*)d_in[33];
  float* out = (float*)d_out;

  // workspace: xemb [1024][256][64] bf16 + 64-short zero pad, hs, hT, dh0, dc0
  unsigned short* xemb = (unsigned short*)d_ws;
  unsigned short* hs   = xemb + (size_t)S_*B_*E_ + 64;       // after pad
  float* hT  = (float*)(hs + (size_t)(S_-1)*B_*H_);
  float* dh0 = hT  + B_*H_;
  float* dc0 = dh0 + B_*H_;

  init_kernel<<<dim3((B_*S_)/4), dim3(256), 0, stream>>>(
      x, init_W, init_b, init_g, init_be, xemb);

  lstm_kernel<<<dim3(64), dim3(512), 0, stream>>>(
      enc_Wih, enc_Whh, enc_bih, enc_bhh, xemb, S_,
      nullptr, nullptr, hT, nullptr);

  latent_kernel<<<dim3(B_), dim3(128), 0, stream>>>(
      hT, eps, mu_W, mu_b, mu_g, mu_be, lv_W, lv_b, lv_g, lv_be,
      lh_W, lh_b, lh_g, lh_be, lc_W, lc_b, lc_g, lc_be, out, dh0, dc0);

  lstm_kernel<<<dim3(64), dim3(512), 0, stream>>>(
      dec_Wih, dec_Whh, dec_bih, dec_bhh, xemb, S_-1,
      dh0, dc0, nullptr, hs);

  out_kernel<<<dim3((B_*(S_-1))/16/4), dim3(256), 0, stream>>>(
      hs, act_W, act_b, time_W, time_b, out);
}